// Round 1
// 437.555 us; speedup vs baseline: 1.1080x; 1.1080x over previous
//
#include <hip/hip_runtime.h>
#include <math.h>

// Full-fidelity emulation of the reference as run by jax-rocm EAGERLY on this
// GPU (x64 on): every op is its own device kernel, all f64 transcendentals
// are __ocml_*_f64 == this kernel's exp()/log(). Crucially BOTH stages are
// inexact because jax lowers exp2(z) -> exp(RN(z*RN(ln2))):
//   DECODE: e = sum(bits * exp2emu(7..0)) accumulates ~1e-13 error; x is then
//           exp2emu(e-127)*(1+frac): x deviates ~1e-13 rel from the true f32
//           -> flips y32 for a handful of values.
//   ENCODE: log2 = log(a)/RN(ln2); exp2(-e) inexact -> mant = W +- eps ->
//           floor ladder emits W-1 garbage / ladder bit flips.
// Sigmoid: exp-form 1/(1+exp(-t)) (ocml).
//
// R1 change (I/O only, numerics byte-identical): the previous version had
// lane-stride-128B global access (each wave dwordx4 touched 64 distinct
// cache lines instead of 16) on BOTH load and store -> request-rate limited
// at 2.8 TB/s despite ideal FETCH+WRITE totals. Now both phases are fully
// coalesced 16B/lane; the value<->lane transpose is done with 3 shfl_xor
// OR-reduces (pack) and a 1KB LDS word exchange (unpack).
__global__ __launch_bounds__(256) void spike_gelu_kernel(
    const uint4* __restrict__ in, uint4* __restrict__ out, int n_vals) {
#pragma clang fp contract(off)
  const double LN2 = 0x1.62e42fefa39efp-1;  // RN(ln2), XLA's folded log(2)

  // Tables (exact ocml-call replicas of the reference's constant arrays):
  //  Wdec[j] = exp2emu(7-j), j=0..7      (decode exponent weights)
  //  Vdec[j] = exp2emu(-(1+j)), j=0..22  (decode fraction weights)
  //  Lm[s]   = exp2emu(-s), s=0..22      (encode ladder scales; ebits use s<=7)
  __shared__ double Wdec[8], Vdec[23], Lm[23];
  __shared__ uint32_t lds_w[256];  // one packed fp32 word per value in block

  const int tid = threadIdx.x;
  if (tid < 8)       Wdec[tid]      = exp((double)(7 - tid) * LN2);
  else if (tid < 31) Vdec[tid - 8]  = exp((double)(7 - tid) * LN2);  // k=-1..-23
  else if (tid < 54) Lm[tid - 31]   = exp((double)(31 - tid) * LN2); // k=0..-22

  // 16B chunks: 8 per value. Block handles 256 values = 2048 chunks = 32KB.
  const int n_chunks = n_vals * 8;
  const int blk_chunk0 = blockIdx.x * 2048;

  // ---- Phase 1: coalesced loads + in-wave bit pack -------------------------
  // Chunk g holds floats of value g/8, nibble position g%8 (MSB-first).
  // For iteration i, thread t: g_local = i*256 + t -> lanes of each 8-lane
  // group hold the 8 nibbles of one value; OR-reduce via shfl_xor.
  const int nibshift = 28 - 4 * (tid & 7);
#pragma unroll
  for (int i = 0; i < 8; ++i) {
    int g = blk_chunk0 + i * 256 + tid;
    uint32_t nib = 0;
    if (g < n_chunks) {
      uint4 b = in[g];
      nib = (((b.x >> 23) & 1u) << 3) | (((b.y >> 23) & 1u) << 2) |
            (((b.z >> 23) & 1u) << 1) | ((b.w >> 23) & 1u);
    }
    uint32_t part = nib << nibshift;
    part |= __shfl_xor(part, 1);
    part |= __shfl_xor(part, 2);
    part |= __shfl_xor(part, 4);
    if ((tid & 7) == 0) lds_w[i * 32 + (tid >> 3)] = part;
  }
  __syncthreads();  // also publishes the exp2emu tables

  // ---- Phase 2: per-value compute (bit-identical to previous version) -----
  const int v = blockIdx.x * 256 + tid;
  uint32_t ob = 0;
  if (v < n_vals) {
    const uint32_t w = lds_w[tid];

    // DECODE exactly as the reference computes it (inexact exp2 weights)
    double sign = (w >> 31) ? -1.0 : 1.0;
    double e_c = 0.0;
#pragma unroll
    for (int j = 0; j < 8; ++j)          // einsum, ascending j (listed order)
      if ((w >> (30 - j)) & 1u) e_c = e_c + Wdec[j];
    double frac_d = 0.0;
#pragma unroll
    for (int j = 0; j < 23; ++j)
      if ((w >> (22 - j)) & 1u) frac_d = frac_d + Vdec[j];

    double x;
    if (e_c > 0.0) {
      double E1 = exp((e_c - 127.0) * LN2);     // exp2emu at non-integer arg
      x = (sign * E1) * (1.0 + frac_d);
    } else {
      x = (sign * exp(-126.0 * LN2)) * frac_d;  // subnormal branch (unused)
    }

    // f64 GELU, exp-form logistic, ocml exp
    double t = 1.702 * x;
    double s = 1.0 / (1.0 + exp(-t));
    double y = x * s;
    float yf = (float)y;        // astype(float32): RN
    double yd = (double)yf;     // astype(float64): exact

    // ENCODE exactly as the reference computes it (inexact exp2/log2)
    double a = fabs(yd);
    if (a > 0.0) {
      if (yd < 0.0) ob |= 0x80000000u;
      double e0 = floor(log(a) / LN2);          // jnp.log2 lowering, ocml log
      e0 = fmin(fmax(e0, -126.0), 127.0);       // jnp.clip
      double eb = e0 + 127.0;
      double p2 = exp(-e0 * LN2);               // exp2emu(-e), ocml exp
      double m1 = a * p2;                       // RN: may be W' +- eps
      double frac_e = m1 - 1.0;                 // Sterbenz-exact
      double mant = frac_e * 8388608.0;         // exact pow2 scale
      // ebits: floor(eb * exp2emu(-s)) mod 2 -> word bits 30..23
#pragma unroll
      for (int sc = 7; sc >= 0; --sc) {
        double f = floor(eb * Lm[sc]);
        double md = f - 2.0 * floor(0.5 * f);
        ob |= ((uint32_t)md) << (23 + sc);
      }
      // mbits: floor(mant * exp2emu(-s)) mod 2 -> word bits 22..0
#pragma unroll
      for (int sc = 22; sc >= 0; --sc) {
        double f = floor(mant * Lm[sc]);
        double md = f - 2.0 * floor(0.5 * f);
        ob |= ((uint32_t)md) << sc;
      }
    }
  }
  lds_w[tid] = ob;  // slot tid touched only by thread tid between barriers
  __syncthreads();

  // ---- Phase 3: coalesced pulse expansion + store --------------------------
  // Chunk g = blk_chunk0 + i*256 + t -> value i*32 + t/8 (broadcast LDS read
  // across each 8-lane group), nibble t&7.
#pragma unroll
  for (int i = 0; i < 8; ++i) {
    int g = blk_chunk0 + i * 256 + tid;
    if (g < n_chunks) {
      uint32_t wv = lds_w[i * 32 + (tid >> 3)];
      int base = 31 - 4 * (tid & 7);
      uint4 o;
      o.x = ((wv >> base) & 1u) * 0x3F800000u;
      o.y = ((wv >> (base - 1)) & 1u) * 0x3F800000u;
      o.z = ((wv >> (base - 2)) & 1u) * 0x3F800000u;
      o.w = ((wv >> (base - 3)) & 1u) * 0x3F800000u;
      out[g] = o;
    }
  }
}

extern "C" void kernel_launch(void* const* d_in, const int* in_sizes, int n_in,
                              void* d_out, int out_size, void* d_ws, size_t ws_size,
                              hipStream_t stream) {
  int n_vals = in_sizes[0] / 32;
  const int block = 256;
  int grid = (n_vals + block - 1) / block;
  spike_gelu_kernel<<<grid, block, 0, stream>>>(
      (const uint4*)d_in[0], (uint4*)d_out, n_vals);
}

// Round 2
// 432.030 us; speedup vs baseline: 1.1221x; 1.0128x over previous
//
#include <hip/hip_runtime.h>
#include <math.h>

// Full-fidelity emulation of the reference as run by jax-rocm EAGERLY on this
// GPU (x64 on): all f64 transcendentals are __ocml_*_f64 == this kernel's
// exp()/log(). Both stages are inexact because jax lowers exp2(z) ->
// exp(RN(z*RN(ln2))) -- we must reproduce that bit-for-bit.
//
// R2 change (numerics bit-identical, VALU thinning): the per-value work that
// depends only on a few bits is precomputed once per launch by a 1-block
// builder kernel into d_ws, then copied to LDS per block:
//   E1tab[256] : decode e_c (ordered Wdec sum) + exp((e_c-127)*LN2), a pure
//                function of the 8-bit exponent byte. E1tab[0] holds the
//                subnormal-branch constant exp(-126*LN2).
//   P2tab[254] : encode exp(-e0*LN2) for integer e0 in [-126,127].
//   EbitsTab   : the 8-step exponent floor-ladder output per eb in [1,254].
// Encode e0 shortcut (proof): for fp32 a with mantissa!=0, |log2(a) - E -
// log2(m)| with log2(m) in [1.7e-7, 1-8.6e-8]; emulated log2 error < 1e-13,
// so floor(log(a)/LN2) == E exactly. Subnormals: log2 <= -126-1.7e-7 ->
// floor <= -127 -> clip == -126 always. Only mantissa==0 (exact powers of
// two, rare) can flip the floor -> keep the original ocml log() path there.
// Mantissa ladder parity: f - 2*floor(0.5*f) == (int)f & 1 for integer f
// (incl. negatives: truncation preserves two's-complement parity).

#define LN2C 0x1.62e42fefa39efp-1  // RN(ln2), XLA's folded log(2)

// d_ws double layout: [0..255]=E1tab, [256..278]=Vdec, [279..301]=Lm,
// [302..555]=P2tab; then 256 uint32 EbitsTab.
__global__ __launch_bounds__(256) void build_tables(double* __restrict__ dt,
                                                    uint32_t* __restrict__ et) {
#pragma clang fp contract(off)
  const double LN2 = LN2C;
  __shared__ double Wdec[8], Lms[23];
  const int t = threadIdx.x;
  if (t < 8) Wdec[t] = exp((double)(7 - t) * LN2);
  if (t >= 31 && t < 54) Lms[t - 31] = exp((double)(31 - t) * LN2);  // 2^-s emu
  __syncthreads();

  // E1tab: replicate the reference's ascending-j einsum accumulation exactly.
  if (t == 0) {
    dt[0] = exp(-126.0 * LN2);  // subnormal-branch scale (e_c==0 case)
    et[0] = 0u;                 // hygiene, never read
  } else {
    double e_c = 0.0;
#pragma unroll
    for (int j = 0; j < 8; ++j)
      if ((t >> (7 - j)) & 1) e_c = e_c + Wdec[j];
    dt[t] = exp((e_c - 127.0) * LN2);
  }
  if (t < 23) dt[256 + t] = exp((double)(-1 - t) * LN2);  // Vdec (same expr)
  if (t < 23) dt[279 + t] = Lms[t];                       // Lm
  if (t < 254) {
    double e0 = (double)(t - 126);
    dt[302 + t] = exp(-e0 * LN2);                         // P2tab
  }
  if (t >= 1 && t < 255) {  // exponent-bit ladder, original formula verbatim
    double eb = (double)t;
    uint32_t r = 0;
#pragma unroll
    for (int sc = 7; sc >= 0; --sc) {
      double f = floor(eb * Lms[sc]);
      double md = f - 2.0 * floor(0.5 * f);
      r |= ((uint32_t)md) << (23 + sc);
    }
    et[t] = r;
  }
}

__global__ __launch_bounds__(256) void spike_gelu_kernel(
    const uint4* __restrict__ in, uint4* __restrict__ out,
    const double* __restrict__ dt, const uint32_t* __restrict__ et,
    int n_vals) {
#pragma clang fp contract(off)
  const double LN2 = LN2C;
  __shared__ double dtab[556];
  __shared__ uint32_t etab[256];
  __shared__ uint32_t lds_w[256];

  const int tid = threadIdx.x;
  // Stage tables global->LDS (coalesced; covered by the phase-1 barrier).
  for (int i = tid; i < 556; i += 256) dtab[i] = dt[i];
  if (tid < 255) etab[tid] = et[tid];

  const int n_chunks = n_vals * 8;
  const int blk_chunk0 = blockIdx.x * 2048;

  // ---- Phase 1: coalesced loads + in-wave bit pack -------------------------
  const int nibshift = 28 - 4 * (tid & 7);
#pragma unroll
  for (int i = 0; i < 8; ++i) {
    int g = blk_chunk0 + i * 256 + tid;
    uint32_t nib = 0;
    if (g < n_chunks) {
      uint4 b = in[g];
      nib = (((b.x >> 23) & 1u) << 3) | (((b.y >> 23) & 1u) << 2) |
            (((b.z >> 23) & 1u) << 1) | ((b.w >> 23) & 1u);
    }
    uint32_t part = nib << nibshift;
    part |= __shfl_xor(part, 1);
    part |= __shfl_xor(part, 2);
    part |= __shfl_xor(part, 4);
    if ((tid & 7) == 0) lds_w[i * 32 + (tid >> 3)] = part;
  }
  __syncthreads();  // publishes lds_w + dtab/etab

  // ---- Phase 2: per-value compute (bit-identical to R1) --------------------
  const int v = blockIdx.x * 256 + tid;
  uint32_t ob = 0;
  if (v < n_vals) {
    const uint32_t w = lds_w[tid];
    const double* E1t  = dtab;
    const double* Vdec = dtab + 256;
    const double* Lm   = dtab + 279;
    const double* P2t  = dtab + 302;

    double sign = (w >> 31) ? -1.0 : 1.0;
    double frac_d = 0.0;
#pragma unroll
    for (int j = 0; j < 23; ++j)
      if ((w >> (22 - j)) & 1u) frac_d = frac_d + Vdec[j];

    const uint32_t eidx = (w >> 23) & 0xFFu;
    double x;
    if (eidx > 0) x = (sign * E1t[eidx]) * (1.0 + frac_d);
    else          x = (sign * E1t[0]) * frac_d;  // subnormal branch (unused)

    // f64 GELU, exp-form logistic, ocml exp
    double t = 1.702 * x;
    double s = 1.0 / (1.0 + exp(-t));
    double y = x * s;
    float yf = (float)y;        // astype(float32): RN
    double yd = (double)yf;     // astype(float64): exact

    // ENCODE with tabled e0/p2/ebits (proof of bit-identity in header)
    double a = fabs(yd);
    if (a > 0.0) {
      if (yd < 0.0) ob |= 0x80000000u;
      uint32_t yb = __float_as_uint(yf);
      uint32_t Ef = (yb >> 23) & 0xFFu;
      uint32_t mb = yb & 0x7FFFFFu;
      int e0i;
      if (Ef == 0u) {
        e0i = -126;              // subnormal: clip lands at -126 exactly
      } else if (mb != 0u) {
        e0i = (int)Ef - 127;     // interior log2: floor == unbiased exponent
      } else {                   // exact power of two: emulated boundary case
        double e0 = floor(log(a) / LN2);
        e0 = fmin(fmax(e0, -126.0), 127.0);
        e0i = (int)e0;
      }
      double p2 = P2t[e0i + 126];   // exp(-e0*LN2), identical ocml value
      double m1 = a * p2;           // RN: may be W' +- eps
      double frac_e = m1 - 1.0;     // Sterbenz-exact
      double mant = frac_e * 8388608.0;
      ob |= etab[e0i + 127];        // the 8-step eb ladder, precomputed
      // mbits: floor(mant * exp2emu(-s)) mod 2 -> word bits 22..0
#pragma unroll
      for (int sc = 22; sc >= 0; --sc) {
        double f = floor(mant * Lm[sc]);
        ob |= (uint32_t)(((int)f) & 1) << sc;  // parity == f - 2*floor(f/2)
      }
    }
  }
  lds_w[tid] = ob;  // slot tid touched only by thread tid between barriers
  __syncthreads();

  // ---- Phase 3: coalesced pulse expansion + store --------------------------
#pragma unroll
  for (int i = 0; i < 8; ++i) {
    int g = blk_chunk0 + i * 256 + tid;
    if (g < n_chunks) {
      uint32_t wv = lds_w[i * 32 + (tid >> 3)];
      int base = 31 - 4 * (tid & 7);
      uint4 o;
      o.x = ((wv >> base) & 1u) * 0x3F800000u;
      o.y = ((wv >> (base - 1)) & 1u) * 0x3F800000u;
      o.z = ((wv >> (base - 2)) & 1u) * 0x3F800000u;
      o.w = ((wv >> (base - 3)) & 1u) * 0x3F800000u;
      out[g] = o;
    }
  }
}

extern "C" void kernel_launch(void* const* d_in, const int* in_sizes, int n_in,
                              void* d_out, int out_size, void* d_ws, size_t ws_size,
                              hipStream_t stream) {
  int n_vals = in_sizes[0] / 32;
  double* dt = (double*)d_ws;
  uint32_t* et = (uint32_t*)((char*)d_ws + 556 * sizeof(double));
  build_tables<<<1, 256, 0, stream>>>(dt, et);
  const int block = 256;
  int grid = (n_vals + block - 1) / block;
  spike_gelu_kernel<<<grid, block, 0, stream>>>(
      (const uint4*)d_in[0], (uint4*)d_out, dt, et, n_vals);
}

// Round 3
// 426.249 us; speedup vs baseline: 1.1374x; 1.0136x over previous
//
#include <hip/hip_runtime.h>
#include <math.h>

// Full-fidelity emulation of the reference as run by jax-rocm EAGERLY on this
// GPU (x64 on): all f64 transcendentals are __ocml_*_f64 == this kernel's
// exp()/log(). Both stages are inexact because jax lowers exp2(z) ->
// exp(RN(z*RN(ln2))) -- reproduced bit-for-bit.
//
// R3 changes (numerics bit-identical, latency-targeted):
//  * 2 values per thread, chains FUSED in straight-line code so the in-order
//    wave issues chain B under chain A's f64/exp latency (R2 showed op-count
//    cuts alone don't move the bench -> latency-bound, not issue-bound).
//  * Mantissa ladder integer shortcut: mant = M + e with |e| <~ 1e-8 by
//    construction (Sterbenz-exact frac, exact 2^23 scale, rel errs ~2^-52).
//    For sc > T=ctz(M): frac part of M*2^-sc is k*2^-sc (k>=1) while total
//    perturbation (M*2^-sc*|delta_Lm| + |e|*2^-sc + RN ulp) <= 2^-sc*2^-25,
//    so floor(mant*Lm[sc]) == M>>sc exactly and its parity is bit sc of M.
//    Only sc <= T (boundary: product can snap across an integer, incl. the
//    pow2 "W-1 garbage" case M=0/T=23) run the original f64 mul+floor.
//  * Nontemporal loads/stores (each byte touched exactly once per launch).
// Encode e0 shortcut (unchanged from R2): mantissa!=0 -> floor(log2emu)==E
// exactly; subnormal -> clip==-126; mantissa==0 (exact pow2) -> rare ocml
// log() path kept verbatim.

#define LN2C 0x1.62e42fefa39efp-1  // RN(ln2), XLA's folded log(2)

typedef unsigned int u32x4 __attribute__((ext_vector_type(4)));

// d_ws double layout: [0..255]=E1tab, [256..278]=Vdec, [279..301]=Lm,
// [302..555]=P2tab; then 256 uint32 EbitsTab.
__global__ __launch_bounds__(256) void build_tables(double* __restrict__ dt,
                                                    uint32_t* __restrict__ et) {
#pragma clang fp contract(off)
  const double LN2 = LN2C;
  __shared__ double Wdec[8], Lms[23];
  const int t = threadIdx.x;
  if (t < 8) Wdec[t] = exp((double)(7 - t) * LN2);
  if (t >= 31 && t < 54) Lms[t - 31] = exp((double)(31 - t) * LN2);  // 2^-s emu
  __syncthreads();

  // E1tab: replicate the reference's ascending-j einsum accumulation exactly.
  if (t == 0) {
    dt[0] = exp(-126.0 * LN2);  // subnormal-branch scale (e_c==0 case)
    et[0] = 0u;                 // hygiene, never read
  } else {
    double e_c = 0.0;
#pragma unroll
    for (int j = 0; j < 8; ++j)
      if ((t >> (7 - j)) & 1) e_c = e_c + Wdec[j];
    dt[t] = exp((e_c - 127.0) * LN2);
  }
  if (t < 23) dt[256 + t] = exp((double)(-1 - t) * LN2);  // Vdec (same expr)
  if (t < 23) dt[279 + t] = Lms[t];                       // Lm
  if (t < 254) {
    double e0 = (double)(t - 126);
    dt[302 + t] = exp(-e0 * LN2);                         // P2tab
  }
  if (t >= 1 && t < 255) {  // exponent-bit ladder, original formula verbatim
    double eb = (double)t;
    uint32_t r = 0;
#pragma unroll
    for (int sc = 7; sc >= 0; --sc) {
      double f = floor(eb * Lms[sc]);
      double md = f - 2.0 * floor(0.5 * f);
      r |= ((uint32_t)md) << (23 + sc);
    }
    et[t] = r;
  }
}

__global__ __launch_bounds__(256) void spike_gelu_kernel(
    const u32x4* __restrict__ in, u32x4* __restrict__ out,
    const double* __restrict__ dt, const uint32_t* __restrict__ et,
    int n_vals) {
#pragma clang fp contract(off)
  const double LN2 = LN2C;
  __shared__ double dtab[556];
  __shared__ uint32_t etab[256];
  __shared__ uint32_t lds_w[512];

  const int tid = threadIdx.x;
  for (int i = tid; i < 556; i += 256) dtab[i] = dt[i];
  etab[tid] = et[tid];

  const int n_chunks = n_vals * 8;
  const int blk_chunk0 = blockIdx.x * 4096;

  // ---- Phase 1: coalesced nt loads (2 in flight) + in-wave bit pack -------
  const int nibshift = 28 - 4 * (tid & 7);
#pragma unroll
  for (int i = 0; i < 8; ++i) {
    int g0 = blk_chunk0 + i * 256 + tid;
    int g1 = g0 + 2048;
    uint32_t nib0 = 0, nib1 = 0;
    if (g0 < n_chunks) {
      u32x4 b = __builtin_nontemporal_load(&in[g0]);
      nib0 = (((b.x >> 23) & 1u) << 3) | (((b.y >> 23) & 1u) << 2) |
             (((b.z >> 23) & 1u) << 1) | ((b.w >> 23) & 1u);
    }
    if (g1 < n_chunks) {
      u32x4 b = __builtin_nontemporal_load(&in[g1]);
      nib1 = (((b.x >> 23) & 1u) << 3) | (((b.y >> 23) & 1u) << 2) |
             (((b.z >> 23) & 1u) << 1) | ((b.w >> 23) & 1u);
    }
    uint32_t p0 = nib0 << nibshift, p1 = nib1 << nibshift;
    p0 |= __shfl_xor(p0, 1);  p1 |= __shfl_xor(p1, 1);
    p0 |= __shfl_xor(p0, 2);  p1 |= __shfl_xor(p1, 2);
    p0 |= __shfl_xor(p0, 4);  p1 |= __shfl_xor(p1, 4);
    if ((tid & 7) == 0) {
      lds_w[i * 32 + (tid >> 3)] = p0;
      lds_w[256 + i * 32 + (tid >> 3)] = p1;
    }
  }
  __syncthreads();  // publishes lds_w + dtab/etab

  // ---- Phase 2: two fused per-value chains --------------------------------
  const int v0 = blockIdx.x * 512 + tid;
  const int v1 = v0 + 256;
  const bool ok0 = v0 < n_vals, ok1 = v1 < n_vals;
  const uint32_t w0 = lds_w[tid], w1 = lds_w[256 + tid];
  const double* E1t  = dtab;
  const double* Vdec = dtab + 256;
  const double* Lm   = dtab + 279;
  const double* P2t  = dtab + 302;

  // DECODE (branchless, both chains interleaved)
  double f0 = 0.0, f1 = 0.0;
#pragma unroll
  for (int j = 0; j < 23; ++j) {
    double vj = Vdec[j];
    if ((w0 >> (22 - j)) & 1u) f0 = f0 + vj;
    if ((w1 >> (22 - j)) & 1u) f1 = f1 + vj;
  }
  uint32_t ei0 = (w0 >> 23) & 0xFFu, ei1 = (w1 >> 23) & 0xFFu;
  double sg0 = (w0 >> 31) ? -1.0 : 1.0, sg1 = (w1 >> 31) ? -1.0 : 1.0;
  double fa0 = ei0 ? (1.0 + f0) : f0, fa1 = ei1 ? (1.0 + f1) : f1;
  double x0 = (sg0 * E1t[ei0]) * fa0, x1 = (sg1 * E1t[ei1]) * fa1;

  // f64 GELU, exp-form logistic, ocml exp (two inlined bodies, adjacent)
  double t0 = 1.702 * x0, t1 = 1.702 * x1;
  double e0v = exp(-t0), e1v = exp(-t1);
  double s0 = 1.0 / (1.0 + e0v), s1 = 1.0 / (1.0 + e1v);
  double y0 = x0 * s0, y1 = x1 * s1;
  float yf0 = (float)y0, yf1 = (float)y1;
  double yd0 = (double)yf0, yd1 = (double)yf1;

  // ENCODE
  double a0 = fabs(yd0), a1 = fabs(yd1);
  uint32_t yb0 = __float_as_uint(yf0), yb1 = __float_as_uint(yf1);
  uint32_t Ef0 = (yb0 >> 23) & 0xFFu, Ef1 = (yb1 >> 23) & 0xFFu;
  uint32_t mbf0 = yb0 & 0x7FFFFFu, mbf1 = yb1 & 0x7FFFFFu;
  int e00 = (Ef0 == 0u) ? -126 : (int)Ef0 - 127;
  int e01 = (Ef1 == 0u) ? -126 : (int)Ef1 - 127;
  bool pw0 = ok0 && (a0 > 0.0) && (Ef0 != 0u) && (mbf0 == 0u);
  bool pw1 = ok1 && (a1 > 0.0) && (Ef1 != 0u) && (mbf1 == 0u);
  if (__builtin_expect(pw0 || pw1, 0)) {  // exact pow2: ocml log boundary
    if (pw0) {
      double e0 = floor(log(a0) / LN2);
      e00 = (int)fmin(fmax(e0, -126.0), 127.0);
    }
    if (pw1) {
      double e0 = floor(log(a1) / LN2);
      e01 = (int)fmin(fmax(e0, -126.0), 127.0);
    }
  }
  double p20 = P2t[e00 + 126], p21 = P2t[e01 + 126];
  double m10 = a0 * p20, m11 = a1 * p21;        // RN: may be W' +- eps
  double mant0 = (m10 - 1.0) * 8388608.0;       // Sterbenz-exact, exact scale
  double mant1 = (m11 - 1.0) * 8388608.0;
  int M0 = (int)rint(mant0), M1 = (int)rint(mant1);
  uint32_t mb0 = ((uint32_t)M0) & 0x7FFFFFu, mb1 = ((uint32_t)M1) & 0x7FFFFFu;
  int T0 = M0 ? __builtin_ctz((uint32_t)M0) : 23;
  int T1 = M1 ? __builtin_ctz((uint32_t)M1) : 23;
  int L0 = T0 < 22 ? T0 : 22, L1 = T1 < 22 ? T1 : 22;
  int Lmax = L0 > L1 ? L0 : L1;
  for (int sc = 0; sc <= Lmax; ++sc) {          // boundary scs: original math
    double lm = Lm[sc];
    if (sc <= L0) {
      double f = floor(mant0 * lm);
      mb0 = (mb0 & ~(1u << sc)) | (((uint32_t)(((int)f) & 1)) << sc);
    }
    if (sc <= L1) {
      double f = floor(mant1 * lm);
      mb1 = (mb1 & ~(1u << sc)) | (((uint32_t)(((int)f) & 1)) << sc);
    }
  }
  uint32_t ob0 = (yb0 & 0x80000000u) | etab[e00 + 127] | mb0;
  uint32_t ob1 = (yb1 & 0x80000000u) | etab[e01 + 127] | mb1;
  ob0 = (ok0 && a0 > 0.0) ? ob0 : 0u;
  ob1 = (ok1 && a1 > 0.0) ? ob1 : 0u;

  lds_w[tid] = ob0;        // slots touched only by this thread between barriers
  lds_w[256 + tid] = ob1;
  __syncthreads();

  // ---- Phase 3: coalesced pulse expansion + nt store ----------------------
#pragma unroll
  for (int i = 0; i < 8; ++i) {
    int g0 = blk_chunk0 + i * 256 + tid;
    int g1 = g0 + 2048;
    int base = 31 - 4 * (tid & 7);
    uint32_t wv0 = lds_w[i * 32 + (tid >> 3)];
    uint32_t wv1 = lds_w[256 + i * 32 + (tid >> 3)];
    if (g0 < n_chunks) {
      u32x4 o;
      o.x = ((wv0 >> base) & 1u) * 0x3F800000u;
      o.y = ((wv0 >> (base - 1)) & 1u) * 0x3F800000u;
      o.z = ((wv0 >> (base - 2)) & 1u) * 0x3F800000u;
      o.w = ((wv0 >> (base - 3)) & 1u) * 0x3F800000u;
      __builtin_nontemporal_store(o, &out[g0]);
    }
    if (g1 < n_chunks) {
      u32x4 o;
      o.x = ((wv1 >> base) & 1u) * 0x3F800000u;
      o.y = ((wv1 >> (base - 1)) & 1u) * 0x3F800000u;
      o.z = ((wv1 >> (base - 2)) & 1u) * 0x3F800000u;
      o.w = ((wv1 >> (base - 3)) & 1u) * 0x3F800000u;
      __builtin_nontemporal_store(o, &out[g1]);
    }
  }
}

extern "C" void kernel_launch(void* const* d_in, const int* in_sizes, int n_in,
                              void* d_out, int out_size, void* d_ws, size_t ws_size,
                              hipStream_t stream) {
  int n_vals = in_sizes[0] / 32;
  double* dt = (double*)d_ws;
  uint32_t* et = (uint32_t*)((char*)d_ws + 556 * sizeof(double));
  build_tables<<<1, 256, 0, stream>>>(dt, et);
  int grid = (n_vals + 511) / 512;
  spike_gelu_kernel<<<grid, 256, 0, stream>>>(
      (const u32x4*)d_in[0], (u32x4*)d_out, dt, et, n_vals);
}

// Round 4
// 419.273 us; speedup vs baseline: 1.1563x; 1.0166x over previous
//
#include <hip/hip_runtime.h>
#include <math.h>

// Full-fidelity emulation of the reference as run by jax-rocm EAGERLY on this
// GPU (x64 on): all f64 transcendentals are __ocml_*_f64 == this kernel's
// exp()/log(). Both stages are inexact because jax lowers exp2(z) ->
// exp(RN(z*RN(ln2))) -- reproduced bit-for-bit.
//
// R4 changes (numerics bit-identical, overhead/structure-targeted):
//  * Builder kernel folded into each block: tables are rebuilt per block with
//    the SAME ocml exp calls in the SAME order (2-3 exps/thread, hidden under
//    the in-flight phase-1 loads). Removes the serialized builder dispatch
//    (~5 us/iteration) and the global table staging.
//  * Wave-independent dataflow: value->lane map v = vbase + (lane&7)*8 +
//    (lane>>3) makes the phase-1 xor-or pack deliver each lane its OWN word
//    (select on i == lane&7, no LDS, no barrier); phase-3 gets the store word
//    with one __shfl from lane (lane&56)+i. The only barriers left are the two
//    table barriers at block start (before any load dependency); load ->
//    compute -> store is fully wave-local so waves stagger for overlap.
//  * Mantissa-ladder integer shortcut + encode-e0 shortcut + pow2 ocml-log
//    boundary path unchanged from R3 (validated absmax==0):
//    - mantissa!=0 -> floor(log(a)/LN2) == E exactly (emu err 1e-13 vs 1.7e-7
//      distance to integer); subnormal -> clip == -126; mantissa==0 -> ocml log.
//    - mant = M + e, |e| <~ 1e-8: for sc > ctz(M), floor(mant*Lm[sc]) == M>>sc
//      exactly -> parity is bit sc of M; only sc <= ctz(M) (incl. pow2 M=0
//      "W-1 garbage" case) run the original f64 mul+floor ladder step.

#define LN2C 0x1.62e42fefa39efp-1  // RN(ln2), XLA's folded log(2)

typedef unsigned int u32x4 __attribute__((ext_vector_type(4)));

__global__ __launch_bounds__(256) void spike_gelu_kernel(
    const u32x4* __restrict__ in, u32x4* __restrict__ out, int n_vals) {
#pragma clang fp contract(off)
  const double LN2 = LN2C;
  // Tables (exact ocml-call replicas of the reference's constant arrays):
  __shared__ double Wdec[8];    // decode exponent weights exp2emu(7..0)
  __shared__ double Lms[23];    // ladder scales exp2emu(0..-22)
  __shared__ double E1t[256];   // decode: ordered Wdec sum -> exp((e_c-127)*LN2)
  __shared__ double Vdec[23];   // decode fraction weights exp2emu(-1..-23)
  __shared__ double P2t[254];   // encode exp(-e0*LN2), e0 in [-126,127]
  __shared__ uint32_t etab[256];// 8-step exponent floor-ladder per eb

  const int tid = threadIdx.x;
  // ---- table stage 1 -------------------------------------------------------
  if (tid < 8) Wdec[tid] = exp((double)(7 - tid) * LN2);
  if (tid >= 31 && tid < 54) Lms[tid - 31] = exp((double)(31 - tid) * LN2);
  __syncthreads();

  // ---- issue phase-1 group-A loads (stay in flight under table stage 2) ---
  const int lane = tid & 63;
  const int vbase = blockIdx.x * 512 + (tid >> 6) * 128;  // wave's 128 values
  const int n_chunks = n_vals * 8;
  const int cbase = vbase * 8 + lane;
  u32x4 bufA[8];
#pragma unroll
  for (int i = 0; i < 8; ++i) {
    int g = cbase + i * 64;
    u32x4 b = {0u, 0u, 0u, 0u};
    if (g < n_chunks) b = __builtin_nontemporal_load(&in[g]);
    bufA[i] = b;
  }

  // ---- table stage 2 (2-3 ocml exps/thread, reference op order) -----------
  if (tid == 0) {
    E1t[0] = exp(-126.0 * LN2);  // subnormal-branch scale (e_c==0)
  } else {
    double e_c = 0.0;
#pragma unroll
    for (int j = 0; j < 8; ++j)   // ascending-j einsum accumulation, verbatim
      if ((tid >> (7 - j)) & 1) e_c = e_c + Wdec[j];
    E1t[tid] = exp((e_c - 127.0) * LN2);
  }
  if (tid < 23) Vdec[tid] = exp((double)(-1 - tid) * LN2);
  if (tid < 254) P2t[tid] = exp((double)(126 - tid) * LN2);  // exp(-e0*LN2)
  if (tid >= 1 && tid < 255) {  // exponent-bit ladder, original formula
    double eb = (double)tid;
    uint32_t r = 0;
#pragma unroll
    for (int sc = 7; sc >= 0; --sc) {
      double f = floor(eb * Lms[sc]);
      double md = f - 2.0 * floor(0.5 * f);
      r |= ((uint32_t)md) << (23 + sc);
    }
    etab[tid] = r;
  } else {
    etab[tid] = 0u;  // hygiene, never read
  }
  __syncthreads();  // tables ready; last block-wide coupling point

  // ---- group-B loads -------------------------------------------------------
  u32x4 bufB[8];
#pragma unroll
  for (int i = 0; i < 8; ++i) {
    int g = cbase + 512 + i * 64;
    u32x4 b = {0u, 0u, 0u, 0u};
    if (g < n_chunks) b = __builtin_nontemporal_load(&in[g]);
    bufB[i] = b;
  }

  // ---- phase 1: wave-local bit pack ---------------------------------------
  // Chunk cbase+i*64+lane has value vbase+i*8+(lane>>3), nibble pos lane&7.
  // After the 3 xor-ors all 8 lanes of group g hold that value's word; with
  // the value->lane map v0 = vbase + (lane&7)*8 + (lane>>3), lane keeps its
  // own word at iteration i == lane&7.
  const int nibshift = 28 - 4 * (lane & 7);
  const int keep = lane & 7;
  uint32_t w0 = 0u, w1 = 0u;
#pragma unroll
  for (int i = 0; i < 8; ++i) {
    u32x4 b = bufA[i];
    uint32_t p = (((((b.x >> 23) & 1u) << 3) | (((b.y >> 23) & 1u) << 2) |
                   (((b.z >> 23) & 1u) << 1) | ((b.w >> 23) & 1u)))
                 << nibshift;
    p |= __shfl_xor(p, 1);
    p |= __shfl_xor(p, 2);
    p |= __shfl_xor(p, 4);
    if (keep == i) w0 = p;
  }
#pragma unroll
  for (int i = 0; i < 8; ++i) {
    u32x4 b = bufB[i];
    uint32_t p = (((((b.x >> 23) & 1u) << 3) | (((b.y >> 23) & 1u) << 2) |
                   (((b.z >> 23) & 1u) << 1) | ((b.w >> 23) & 1u)))
                 << nibshift;
    p |= __shfl_xor(p, 1);
    p |= __shfl_xor(p, 2);
    p |= __shfl_xor(p, 4);
    if (keep == i) w1 = p;
  }

  // ---- phase 2: two fused per-value chains (bit-identical to R3) ----------
  const int v0 = vbase + (lane & 7) * 8 + (lane >> 3);
  const int v1 = v0 + 64;
  const bool ok0 = v0 < n_vals, ok1 = v1 < n_vals;

  // DECODE (branchless, both chains interleaved)
  double f0 = 0.0, f1 = 0.0;
#pragma unroll
  for (int j = 0; j < 23; ++j) {
    double vj = Vdec[j];
    if ((w0 >> (22 - j)) & 1u) f0 = f0 + vj;
    if ((w1 >> (22 - j)) & 1u) f1 = f1 + vj;
  }
  uint32_t ei0 = (w0 >> 23) & 0xFFu, ei1 = (w1 >> 23) & 0xFFu;
  double sg0 = (w0 >> 31) ? -1.0 : 1.0, sg1 = (w1 >> 31) ? -1.0 : 1.0;
  double fa0 = ei0 ? (1.0 + f0) : f0, fa1 = ei1 ? (1.0 + f1) : f1;
  double x0 = (sg0 * E1t[ei0]) * fa0, x1 = (sg1 * E1t[ei1]) * fa1;

  // f64 GELU, exp-form logistic, ocml exp (two inlined bodies, adjacent)
  double t0 = 1.702 * x0, t1 = 1.702 * x1;
  double e0v = exp(-t0), e1v = exp(-t1);
  double s0 = 1.0 / (1.0 + e0v), s1 = 1.0 / (1.0 + e1v);
  double y0 = x0 * s0, y1 = x1 * s1;
  float yf0 = (float)y0, yf1 = (float)y1;
  double yd0 = (double)yf0, yd1 = (double)yf1;

  // ENCODE
  double a0 = fabs(yd0), a1 = fabs(yd1);
  uint32_t yb0 = __float_as_uint(yf0), yb1 = __float_as_uint(yf1);
  uint32_t Ef0 = (yb0 >> 23) & 0xFFu, Ef1 = (yb1 >> 23) & 0xFFu;
  uint32_t mbf0 = yb0 & 0x7FFFFFu, mbf1 = yb1 & 0x7FFFFFu;
  int e00 = (Ef0 == 0u) ? -126 : (int)Ef0 - 127;
  int e01 = (Ef1 == 0u) ? -126 : (int)Ef1 - 127;
  bool pw0 = ok0 && (a0 > 0.0) && (Ef0 != 0u) && (mbf0 == 0u);
  bool pw1 = ok1 && (a1 > 0.0) && (Ef1 != 0u) && (mbf1 == 0u);
  if (__builtin_expect(pw0 || pw1, 0)) {  // exact pow2: ocml log boundary
    if (pw0) {
      double e0 = floor(log(a0) / LN2);
      e00 = (int)fmin(fmax(e0, -126.0), 127.0);
    }
    if (pw1) {
      double e0 = floor(log(a1) / LN2);
      e01 = (int)fmin(fmax(e0, -126.0), 127.0);
    }
  }
  double p20 = P2t[e00 + 126], p21 = P2t[e01 + 126];
  double m10 = a0 * p20, m11 = a1 * p21;        // RN: may be W' +- eps
  double mant0 = (m10 - 1.0) * 8388608.0;       // Sterbenz-exact, exact scale
  double mant1 = (m11 - 1.0) * 8388608.0;
  int M0 = (int)rint(mant0), M1 = (int)rint(mant1);
  uint32_t mb0 = ((uint32_t)M0) & 0x7FFFFFu, mb1 = ((uint32_t)M1) & 0x7FFFFFu;
  int T0 = M0 ? __builtin_ctz((uint32_t)M0) : 23;
  int T1 = M1 ? __builtin_ctz((uint32_t)M1) : 23;
  int L0 = T0 < 22 ? T0 : 22, L1 = T1 < 22 ? T1 : 22;
  int Lmax = L0 > L1 ? L0 : L1;
  for (int sc = 0; sc <= Lmax; ++sc) {          // boundary scs: original math
    double lm = Lms[sc];
    if (sc <= L0) {
      double f = floor(mant0 * lm);
      mb0 = (mb0 & ~(1u << sc)) | (((uint32_t)(((int)f) & 1)) << sc);
    }
    if (sc <= L1) {
      double f = floor(mant1 * lm);
      mb1 = (mb1 & ~(1u << sc)) | (((uint32_t)(((int)f) & 1)) << sc);
    }
  }
  uint32_t ob0 = (yb0 & 0x80000000u) | etab[e00 + 127] | mb0;
  uint32_t ob1 = (yb1 & 0x80000000u) | etab[e01 + 127] | mb1;
  ob0 = (ok0 && a0 > 0.0) ? ob0 : 0u;
  ob1 = (ok1 && a1 > 0.0) ? ob1 : 0u;

  // ---- phase 3: wave-local pulse expansion + nt store ---------------------
  // Chunk cbase+i*64+lane needs value vbase+i*8+(lane>>3), held at lane
  // (lane&56)+i under the phase-2 map.
#pragma unroll
  for (int i = 0; i < 8; ++i) {
    int g0 = cbase + i * 64;
    int g1 = g0 + 512;
    int src = (lane & 56) + i;
    uint32_t wa = __shfl(ob0, src);
    uint32_t wb = __shfl(ob1, src);
    int base = 31 - 4 * (lane & 7);
    if (g0 < n_chunks) {
      u32x4 o;
      o.x = ((wa >> base) & 1u) * 0x3F800000u;
      o.y = ((wa >> (base - 1)) & 1u) * 0x3F800000u;
      o.z = ((wa >> (base - 2)) & 1u) * 0x3F800000u;
      o.w = ((wa >> (base - 3)) & 1u) * 0x3F800000u;
      __builtin_nontemporal_store(o, &out[g0]);
    }
    if (g1 < n_chunks) {
      u32x4 o;
      o.x = ((wb >> base) & 1u) * 0x3F800000u;
      o.y = ((wb >> (base - 1)) & 1u) * 0x3F800000u;
      o.z = ((wb >> (base - 2)) & 1u) * 0x3F800000u;
      o.w = ((wb >> (base - 3)) & 1u) * 0x3F800000u;
      __builtin_nontemporal_store(o, &out[g1]);
    }
  }
}

extern "C" void kernel_launch(void* const* d_in, const int* in_sizes, int n_in,
                              void* d_out, int out_size, void* d_ws, size_t ws_size,
                              hipStream_t stream) {
  int n_vals = in_sizes[0] / 32;
  int grid = (n_vals + 511) / 512;
  spike_gelu_kernel<<<grid, 256, 0, stream>>>(
      (const u32x4*)d_in[0], (u32x4*)d_out, n_vals);
}